// Round 9
// baseline (197.324 us; speedup 1.0000x reference)
//
#include <hip/hip_runtime.h>
#include <math.h>

#define SELU_SCALE 1.0507009873554804934193349852946f
#define SELU_ALPHA 1.6732632423543772848170429916717f

typedef short bf16x8 __attribute__((ext_vector_type(8)));
typedef float f32x4 __attribute__((ext_vector_type(4)));

__device__ __forceinline__ float selu_f(float x) {
    return SELU_SCALE * (x > 0.f ? x : SELU_ALPHA * expm1f(x));
}

__device__ __forceinline__ unsigned short f2bf(float f) {
    unsigned int u = __float_as_uint(f);
    u += 0x7FFF + ((u >> 16) & 1);  // round-to-nearest-even
    return (unsigned short)(u >> 16);
}
__device__ __forceinline__ float bflo(unsigned int u) { return __uint_as_float(u << 16); }
__device__ __forceinline__ float bfhi(unsigned int u) { return __uint_as_float(u & 0xFFFF0000u); }

// monotonic float<->uint encoding (order-preserving); max in uint == max in float
__device__ __forceinline__ unsigned int fenc(float f) {
    unsigned int u = __float_as_uint(f);
    return (u & 0x80000000u) ? ~u : (u | 0x80000000u);
}
__device__ __forceinline__ float fdec(unsigned int u) {
    return __uint_as_float((u & 0x80000000u) ? (u ^ 0x80000000u) : ~u);
}

__device__ __forceinline__ void acc8(float* a, uint4 v) {
    a[0] += bflo(v.x); a[1] += bfhi(v.x);
    a[2] += bflo(v.y); a[3] += bfhi(v.y);
    a[4] += bflo(v.z); a[5] += bfhi(v.z);
    a[6] += bflo(v.w); a[7] += bfhi(v.w);
}

__device__ __forceinline__ uint4 pack8(const float* a, float dv) {
    uint4 pk;
    pk.x = (unsigned int)f2bf(a[0] * dv) | ((unsigned int)f2bf(a[1] * dv) << 16);
    pk.y = (unsigned int)f2bf(a[2] * dv) | ((unsigned int)f2bf(a[3] * dv) << 16);
    pk.z = (unsigned int)f2bf(a[4] * dv) | ((unsigned int)f2bf(a[5] * dv) << 16);
    pk.w = (unsigned int)f2bf(a[6] * dv) | ((unsigned int)f2bf(a[7] * dv) << 16);
    return pk;
}

// 16-deep gather step: issues 16 independent uint4 loads (slot order j..j+15)
// then accumulates in the same sequential order as two 8-batches.
template <int TPN>
__device__ __forceinline__ void gather16(const uint4* hp, const int* sp, int j,
                                         int cq, float* a) {
    int4 sa = *(const int4*)&sp[j];
    int4 sb = *(const int4*)&sp[j + 4];
    int4 sc = *(const int4*)&sp[j + 8];
    int4 sd = *(const int4*)&sp[j + 12];
    uint4 v0 = hp[(size_t)sa.x * TPN + cq];
    uint4 v1 = hp[(size_t)sa.y * TPN + cq];
    uint4 v2 = hp[(size_t)sa.z * TPN + cq];
    uint4 v3 = hp[(size_t)sa.w * TPN + cq];
    uint4 v4 = hp[(size_t)sb.x * TPN + cq];
    uint4 v5 = hp[(size_t)sb.y * TPN + cq];
    uint4 v6 = hp[(size_t)sb.z * TPN + cq];
    uint4 v7 = hp[(size_t)sb.w * TPN + cq];
    uint4 v8 = hp[(size_t)sc.x * TPN + cq];
    uint4 v9 = hp[(size_t)sc.y * TPN + cq];
    uint4 va = hp[(size_t)sc.z * TPN + cq];
    uint4 vb = hp[(size_t)sc.w * TPN + cq];
    uint4 vc = hp[(size_t)sd.x * TPN + cq];
    uint4 vd = hp[(size_t)sd.y * TPN + cq];
    uint4 ve = hp[(size_t)sd.z * TPN + cq];
    uint4 vf = hp[(size_t)sd.w * TPN + cq];
    acc8(a, v0); acc8(a, v1); acc8(a, v2); acc8(a, v3);
    acc8(a, v4); acc8(a, v5); acc8(a, v6); acc8(a, v7);
    acc8(a, v8); acc8(a, v9); acc8(a, va); acc8(a, vb);
    acc8(a, vc); acc8(a, vd); acc8(a, ve); acc8(a, vf);
}

template <int TPN>
__device__ __forceinline__ void gather8(const uint4* hp, const int* sp, int j,
                                        int cq, float* a) {
    int4 sa = *(const int4*)&sp[j];
    int4 sb = *(const int4*)&sp[j + 4];
    uint4 v0 = hp[(size_t)sa.x * TPN + cq];
    uint4 v1 = hp[(size_t)sa.y * TPN + cq];
    uint4 v2 = hp[(size_t)sa.z * TPN + cq];
    uint4 v3 = hp[(size_t)sa.w * TPN + cq];
    uint4 v4 = hp[(size_t)sb.x * TPN + cq];
    uint4 v5 = hp[(size_t)sb.y * TPN + cq];
    uint4 v6 = hp[(size_t)sb.z * TPN + cq];
    uint4 v7 = hp[(size_t)sb.w * TPN + cq];
    acc8(a, v0); acc8(a, v1); acc8(a, v2); acc8(a, v3);
    acc8(a, v4); acc8(a, v5); acc8(a, v6); acc8(a, v7);
}

// ---------------------------------------------------------------------------
// prep: blocks 0..127 zero cnt; block 128 zeros sentinel rows + m_enc;
// blocks 129..272 pack weights into MFMA B-fragment layout.
// ---------------------------------------------------------------------------
__global__ __launch_bounds__(256) void prep_kernel(
    int* __restrict__ cnt, unsigned int* __restrict__ pad1,
    unsigned int* __restrict__ pad2, unsigned int* __restrict__ menc,
    const float* __restrict__ W1, unsigned short* __restrict__ Wp1,
    const float* __restrict__ W2, unsigned short* __restrict__ Wp2) {
    int b = blockIdx.x;
    int t = threadIdx.x;
    if (b < 128) {
        cnt[b * 256 + t] = 0;
    } else if (b == 128) {
        if (t < 32) pad1[t] = 0;   // hs1 sentinel row (64 bf16)
        if (t < 64) pad2[t] = 0;   // hs2 sentinel row (128 bf16)
        for (int i = t; i < 4096; i += 256) menc[i] = 0u;  // enc-min
    } else {
        if (t >= 64) return;
        int fb = b - 129;
        const float* W; unsigned short* Wp; int K, N, f;
        if (fb < 16) { W = W1; Wp = Wp1; K = 64; N = 128; f = fb; }
        else         { W = W2; Wp = Wp2; K = 128; N = 512; f = fb - 16; }
        int l = t;  // 0..63
        int KS = K / 32;
        int nt = f / KS, ks = f % KS;
        int ncol = nt * 16 + (l & 15);
        int k0 = ks * 32 + (l >> 4) * 8;
        unsigned short v[8];
        #pragma unroll
        for (int j = 0; j < 8; j++) v[j] = f2bf(W[(size_t)(k0 + j) * N + ncol]);
        *(uint4*)&Wp[((size_t)f * 64 + l) * 8] = *(uint4*)v;
    }
}

// ---------------------------------------------------------------------------
// count + scatter in one pass (verified r3): atomicAdd slot IS the position.
// ---------------------------------------------------------------------------
__global__ __launch_bounds__(256) void count_scatter_kernel(
    const int* __restrict__ src, const int* __restrict__ dst,
    int* __restrict__ cnt, int* __restrict__ ssrc, int E) {
    int e = blockIdx.x * 256 + threadIdx.x;
    if (e >= E) return;
    int d = dst[e];
    int pos = atomicAdd(&cnt[d], 1);
    if (pos < 64) ssrc[((size_t)d << 6) + pos] = src[e];
}

// ---------------------------------------------------------------------------
// padfill + cov/encoder fused (verified r4).  256 blocks x 128 threads.
// ---------------------------------------------------------------------------
__global__ __launch_bounds__(128) void padfill_cov_kernel(
    const int* __restrict__ cnt, float* __restrict__ dinv,
    int* __restrict__ pcnt, int* __restrict__ ssrc, int n,
    const float* __restrict__ x, const float* __restrict__ w_e1,
    const float* __restrict__ b_e1, unsigned short* __restrict__ hs1) {
    __shared__ float Wl[12 * 64];
    __shared__ float Bl[64];
    __shared__ float xs[152 * 3];
    int t = threadIdx.x;
    int p0 = blockIdx.x * 128;
    int p = p0 + t;

    // ---- padfill part (in-register dinv) ----
    int c = cnt[p];
    float dv = rsqrtf((float)(c + 1));
    dinv[p] = dv;
    int pc = (c + 7) & ~7;
    if (pc > 64) pc = 64;
    pcnt[p] = pc;
    {
        int* row = ssrc + ((size_t)p << 6);
        for (int k = c; k < pc; k++) row[k] = n;  // sentinel zero-row
    }

    // ---- cov + encoder part ----
    for (int i = t; i < 768; i += 128) Wl[i] = w_e1[i];
    if (t < 64) Bl[t] = b_e1[t];
    int n0 = p0 & 4095;
    const float* xb = x + (size_t)(p0 - n0) * 3;  // batch base (128 | 4096)
    for (int idx = t; idx < 456; idx += 128) {    // (128+24) slots x 3
        int slot = idx / 3, d = idx - slot * 3;
        int g = n0 - 12 + slot;
        g = g < 0 ? 0 : (g > 4095 ? 4095 : g);
        xs[idx] = xb[g * 3 + d];
    }
    __syncthreads();
    int nn = n0 + t;
    int lo = nn - 12 < 0 ? 0 : nn - 12;
    int hi = nn + 12 > 4095 ? 4095 : nn + 12;
    int slo = lo - n0 + 12, shi = hi - n0 + 12;
    float sx = 0.f, sy = 0.f, sz = 0.f;
    float sxx = 0.f, sxy = 0.f, sxz = 0.f, syy = 0.f, syz = 0.f, szz = 0.f;
    for (int s = slo; s <= shi; s++) {
        float xv = xs[s * 3 + 0], yv = xs[s * 3 + 1], zv = xs[s * 3 + 2];
        sx += xv; sy += yv; sz += zv;
        sxx = fmaf(xv, xv, sxx); sxy = fmaf(xv, yv, sxy); sxz = fmaf(xv, zv, sxz);
        syy = fmaf(yv, yv, syy); syz = fmaf(yv, zv, syz); szz = fmaf(zv, zv, szz);
    }
    float cntf = (float)(shi - slo + 1);
    float rin = 1.f / cntf;
    float mx = sx * rin, my = sy * rin, mz = sz * rin;
    const float inv23 = 1.f / 23.f;
    float c00 = (sxx - sx * mx) * inv23;
    float c01 = (sxy - sx * my) * inv23;
    float c02 = (sxz - sx * mz) * inv23;
    float c11 = (syy - sy * my) * inv23;
    float c12 = (syz - sy * mz) * inv23;
    float c22 = (szz - sz * mz) * inv23;
    float feat[12];
    feat[0] = xs[(t + 12) * 3 + 0];
    feat[1] = xs[(t + 12) * 3 + 1];
    feat[2] = xs[(t + 12) * 3 + 2];
    feat[3] = c00; feat[4] = c01; feat[5]  = c02;
    feat[6] = c01; feat[7] = c11; feat[8]  = c12;
    feat[9] = c02; feat[10] = c12; feat[11] = c22;
    unsigned int* hp = (unsigned int*)(hs1 + (size_t)p * 64);
    for (int cc = 0; cc < 64; cc += 2) {
        float a0 = Bl[cc], a1 = Bl[cc + 1];
        #pragma unroll
        for (int i = 0; i < 12; i++) {
            a0 = fmaf(feat[i], Wl[i * 64 + cc], a0);
            a1 = fmaf(feat[i], Wl[i * 64 + cc + 1], a1);
        }
        unsigned int pk = (unsigned int)f2bf(dv * selu_f(a0)) |
                          ((unsigned int)f2bf(dv * selu_f(a1)) << 16);
        hp[cc >> 1] = pk;
    }
}

// ---------------------------------------------------------------------------
// GCN1 fused (verified r6): gather(64ch, 16-deep) into LDS, MFMA K=64 N=128.
// ---------------------------------------------------------------------------
__global__ __launch_bounds__(256) void agg_gemm1_kernel(
    const unsigned short* __restrict__ hs, const float* __restrict__ dinv,
    const int* __restrict__ pcnt, const int* __restrict__ ssrc,
    const unsigned short* __restrict__ Wp, const float* __restrict__ bias,
    unsigned short* __restrict__ hs2) {
    constexpr int LDA = 72;  // 64 + 8 bf16 pad
    __shared__ unsigned short As[64 * LDA];
    int t = threadIdx.x;
    int R0 = blockIdx.x * 64;
    const uint4* hp = (const uint4*)hs;

    // ---- gather phase: TPN=8, 32 nodes per pass, 2 passes ----
    #pragma unroll
    for (int pass = 0; pass < 2; pass++) {
        int rloc = pass * 32 + (t >> 3);
        int node = R0 + rloc;
        int cq = t & 7;
        float a[8];
        {
            uint4 u = hp[(size_t)node * 8 + cq];
            a[0] = bflo(u.x); a[1] = bfhi(u.x);
            a[2] = bflo(u.y); a[3] = bfhi(u.y);
            a[4] = bflo(u.z); a[5] = bfhi(u.z);
            a[6] = bflo(u.w); a[7] = bfhi(u.w);
        }
        int pc = pcnt[node];
        const int* sp = ssrc + ((size_t)node << 6);
        int j = 0;
        for (; j + 16 <= pc; j += 16) gather16<8>(hp, sp, j, cq, a);
        if (j < pc) gather8<8>(hp, sp, j, cq, a);
        *(uint4*)&As[rloc * LDA + cq * 8] = pack8(a, dinv[node]);
    }
    __syncthreads();

    // ---- MFMA phase: 4 waves x 16 rows ----
    int wave = t >> 6, l = t & 63;
    int ml = l & 15, q = l >> 4;
    int wr = wave * 16;
    f32x4 acc[8];
    #pragma unroll
    for (int nf = 0; nf < 8; nf++) acc[nf] = (f32x4){0.f, 0.f, 0.f, 0.f};
    const bf16x8* wp8 = (const bf16x8*)Wp;
    #pragma unroll
    for (int ks = 0; ks < 2; ks++) {
        bf16x8 af = *(const bf16x8*)&As[(wr + ml) * LDA + ks * 32 + q * 8];
        bf16x8 bfr[8];
        #pragma unroll
        for (int nf = 0; nf < 8; nf++)
            bfr[nf] = wp8[(size_t)(nf * 2 + ks) * 64 + l];
        #pragma unroll
        for (int nf = 0; nf < 8; nf++)
            acc[nf] = __builtin_amdgcn_mfma_f32_16x16x32_bf16(
                af, bfr[nf], acc[nf], 0, 0, 0);
    }
    float bj[8];
    #pragma unroll
    for (int nf = 0; nf < 8; nf++) bj[nf] = bias[nf * 16 + ml];
    #pragma unroll
    for (int r = 0; r < 4; r++) {
        int row = R0 + wr + q * 4 + r;
        float dv = dinv[row];
        #pragma unroll
        for (int nf = 0; nf < 8; nf++) {
            float v = dv * selu_f(acc[nf][r] + bj[nf]);
            hs2[(size_t)row * 128 + nf * 16 + ml] = f2bf(v);
        }
    }
}

// ---------------------------------------------------------------------------
// GCN2 fused (r6 wave mapping + single-barrier reduce): gather(128ch,
// 16-deep) into LDS once, loop 4 column-blocks of the K=128 N=512 MFMA.
// redf is [4 waves][512 cols] so each slot is written once -> ONE barrier
// (was 8); invariant A-fragments hoisted out of the cbi loop.  Max exact.
// ---------------------------------------------------------------------------
__global__ __launch_bounds__(256) void agg_gemm2_kernel(
    const unsigned short* __restrict__ hs, const float* __restrict__ dinv,
    const int* __restrict__ pcnt, const int* __restrict__ ssrc,
    const unsigned short* __restrict__ Wp, const float* __restrict__ bias,
    unsigned int* __restrict__ menc) {
    constexpr int KS = 4;
    constexpr int LDA = 136;  // 128 + 8
    __shared__ unsigned short As[64 * LDA];
    __shared__ float redf[4 * 512];  // [wave][col]
    int t = threadIdx.x;
    int R0 = blockIdx.x * 64;
    const uint4* hp = (const uint4*)hs;

    // ---- gather phase: TPN=16, 16 nodes per pass, 4 passes ----
    #pragma unroll
    for (int pass = 0; pass < 4; pass++) {
        int rloc = pass * 16 + (t >> 4);
        int node = R0 + rloc;
        int cq = t & 15;
        float a[8];
        {
            uint4 u = hp[(size_t)node * 16 + cq];
            a[0] = bflo(u.x); a[1] = bfhi(u.x);
            a[2] = bflo(u.y); a[3] = bfhi(u.y);
            a[4] = bflo(u.z); a[5] = bfhi(u.z);
            a[6] = bflo(u.w); a[7] = bfhi(u.w);
        }
        int pc = pcnt[node];
        const int* sp = ssrc + ((size_t)node << 6);
        int j = 0;
        for (; j + 16 <= pc; j += 16) gather16<16>(hp, sp, j, cq, a);
        if (j < pc) gather8<16>(hp, sp, j, cq, a);
        *(uint4*)&As[rloc * LDA + cq * 8] = pack8(a, dinv[node]);
    }
    __syncthreads();

    // ---- MFMA phase: 4 waves x 16 rows, loop over 4 column-blocks ----
    int wave = t >> 6, l = t & 63;
    int ml = l & 15, q = l >> 4;
    int wr = wave * 16;
    int b = blockIdx.x >> 6;  // 64 row-tiles per batch
    const bf16x8* wp8 = (const bf16x8*)Wp;

    // hoist A fragments (invariant across cbi)
    bf16x8 af[KS];
    #pragma unroll
    for (int ks = 0; ks < KS; ks++)
        af[ks] = *(const bf16x8*)&As[(wr + ml) * LDA + ks * 32 + q * 8];

    #pragma unroll
    for (int cbi = 0; cbi < 4; cbi++) {
        f32x4 acc[8];
        #pragma unroll
        for (int nf = 0; nf < 8; nf++) acc[nf] = (f32x4){0.f, 0.f, 0.f, 0.f};
        #pragma unroll
        for (int ks = 0; ks < KS; ks++) {
            bf16x8 bfr[8];
            #pragma unroll
            for (int nf = 0; nf < 8; nf++)
                bfr[nf] = wp8[(size_t)((cbi * 8 + nf) * KS + ks) * 64 + l];
            #pragma unroll
            for (int nf = 0; nf < 8; nf++)
                acc[nf] = __builtin_amdgcn_mfma_f32_16x16x32_bf16(
                    af[ks], bfr[nf], acc[nf], 0, 0, 0);
        }
        // selu + column max over this wave's 16 rows; C/D: col=ml, row=q*4+r
        #pragma unroll
        for (int nf = 0; nf < 8; nf++) {
            float bj = bias[cbi * 128 + nf * 16 + ml];
            float v = -INFINITY;
            #pragma unroll
            for (int r = 0; r < 4; r++)
                v = fmaxf(v, selu_f(acc[nf][r] + bj));
            v = fmaxf(v, __shfl_xor(v, 16, 64));
            v = fmaxf(v, __shfl_xor(v, 32, 64));
            if (ml == l) redf[wave * 512 + cbi * 128 + nf * 16 + l] = v;
        }
    }
    __syncthreads();  // single barrier: every redf slot written exactly once
    // final: cross-wave max + atomicMax; t covers cols t and t+256
    #pragma unroll
    for (int cc = 0; cc < 2; cc++) {
        int col = t + cc * 256;
        float v = fmaxf(fmaxf(redf[col], redf[512 + col]),
                        fmaxf(redf[1024 + col], redf[1536 + col]));
        atomicMax(&menc[b * 512 + col], fenc(v));
    }
}

// ---------------------------------------------------------------------------
// lat: grid (8 batches, 16 col-groups of 32).  lat[b][c] =
// selu(sum_k m[b][k]*w_e2[k][c] + b_e2[c]).  k split 8 ways, LDS reduce.
// ---------------------------------------------------------------------------
__global__ __launch_bounds__(256) void lat_kernel(
    const unsigned int* __restrict__ menc, const float* __restrict__ w_e2,
    const float* __restrict__ b_e2, float* __restrict__ lat) {
    int b = blockIdx.x;
    int cg = blockIdx.y;
    int t = threadIdx.x;
    __shared__ float ml[512];
    __shared__ float red[8][32];
    ml[t] = fdec(menc[b * 512 + t]);
    ml[t + 256] = fdec(menc[b * 512 + t + 256]);
    __syncthreads();
    int cl = t & 31;          // column within group
    int kg = t >> 5;          // 0..7, k-chunks of 64
    int c = cg * 32 + cl;
    const float* wp = w_e2 + (size_t)(kg * 64) * 512 + c;
    const float* mlp = ml + kg * 64;
    float acc = 0.f;
    #pragma unroll 16
    for (int k = 0; k < 64; k++) acc = fmaf(mlp[k], wp[(size_t)k * 512], acc);
    red[kg][cl] = acc;
    __syncthreads();
    if (t < 32) {
        float v = ((red[0][t] + red[1][t]) + (red[2][t] + red[3][t])) +
                  ((red[4][t] + red[5][t]) + (red[6][t] + red[7][t]));
        lat[b * 512 + cg * 32 + t] = selu_f(v + b_e2[cg * 32 + t]);
    }
}

// ---------------------------------------------------------------------------
// latw + decode: 64 blocks = 8 batches x 8 point-slices.  Each block
// recomputes the tiny latw reduction (512x6) then decodes its 512 points.
// ---------------------------------------------------------------------------
__global__ __launch_bounds__(256) void latw_decode_kernel(
    const float* __restrict__ lat, const float* __restrict__ w_d1,
    const float* __restrict__ b_d1, const float* __restrict__ w_d2,
    const float* __restrict__ b_d2, float* __restrict__ out) {
    int b = blockIdx.x >> 3;   // batch
    int sl = blockIdx.x & 7;   // point slice
    int t = threadIdx.x;
    __shared__ float ll[512];
    __shared__ float red[6][256];
    __shared__ float lw[6];
    ll[t] = lat[b * 512 + t];
    ll[t + 256] = lat[b * 512 + t + 256];
    __syncthreads();
    float p[6] = {0.f, 0.f, 0.f, 0.f, 0.f, 0.f};
    for (int k = t; k < 512; k += 256) {
        float lv = ll[k];
        #pragma unroll
        for (int j = 0; j < 3; j++) {
            p[j]     = fmaf(lv, w_d1[k * 3 + j], p[j]);
            p[3 + j] = fmaf(lv, w_d2[k * 3 + j], p[3 + j]);
        }
    }
    #pragma unroll
    for (int j = 0; j < 6; j++) red[j][t] = p[j];
    __syncthreads();
    for (int s = 128; s > 0; s >>= 1) {
        if (t < s) {
            #pragma unroll
            for (int j = 0; j < 6; j++) red[j][t] += red[j][t + s];
        }
        __syncthreads();
    }
    if (t < 3) {
        lw[t]     = red[t][0] + b_d1[t];
        lw[3 + t] = red[3 + t][0] + b_d2[t];
    }
    __syncthreads();
    float l10 = lw[0], l11 = lw[1], l12 = lw[2];
    float l20 = lw[3], l21 = lw[4], l22 = lw[5];
    float w1a0 = w_d1[1536 + 0], w1a1 = w_d1[1536 + 1], w1a2 = w_d1[1536 + 2];
    float w1b0 = w_d1[1539 + 0], w1b1 = w_d1[1539 + 1], w1b2 = w_d1[1539 + 2];
    float w2a0 = w_d2[1536 + 0], w2a1 = w_d2[1536 + 1], w2a2 = w_d2[1536 + 2];
    float w2b0 = w_d2[1539 + 0], w2b1 = w_d2[1539 + 1], w2b2 = w_d2[1539 + 2];
    float w2c0 = w_d2[1542 + 0], w2c1 = w_d2[1542 + 1], w2c2 = w_d2[1542 + 2];
    {
        int n = sl * 512 + t;
        #pragma unroll
        for (int half = 0; half < 2; half++) {
            int i = n / 46;
            int j = n - i * 46;
            float y0 = fmaf((float)i, 119.f / 90.f, 1.f);
            float y1 = fmaf((float)j, 59.f / 45.f, 1.f);
            float k0 = selu_f(l10 + y0 * w1a0 + y1 * w1b0);
            float k1 = selu_f(l11 + y0 * w1a1 + y1 * w1b1);
            float k2 = selu_f(l12 + y0 * w1a2 + y1 * w1b2);
            float o0 = selu_f(l20 + k0 * w2a0 + k1 * w2b0 + k2 * w2c0);
            float o1 = selu_f(l21 + k0 * w2a1 + k1 * w2b1 + k2 * w2c1);
            float o2 = selu_f(l22 + k0 * w2a2 + k1 * w2b2 + k2 * w2c2);
            size_t pidx = (size_t)(b * 4096 + n) * 3;
            out[pidx + 0] = o0;
            out[pidx + 1] = o1;
            out[pidx + 2] = o2;
            n += 256;
        }
    }
}

// ---------------------------------------------------------------------------
extern "C" void kernel_launch(void* const* d_in, const int* in_sizes, int n_in,
                              void* d_out, int out_size, void* d_ws, size_t ws_size,
                              hipStream_t stream) {
    const float* x    = (const float*)d_in[0];
    const int*   knn  = (const int*)d_in[1];
    const float* w_e1 = (const float*)d_in[2];
    const float* b_e1 = (const float*)d_in[3];
    const float* w_g1 = (const float*)d_in[4];
    const float* b_g1 = (const float*)d_in[5];
    const float* w_g2 = (const float*)d_in[6];
    const float* b_g2 = (const float*)d_in[7];
    const float* w_e2 = (const float*)d_in[8];
    const float* b_e2 = (const float*)d_in[9];
    const float* w_d1 = (const float*)d_in[10];
    const float* b_d1 = (const float*)d_in[11];
    const float* w_d2 = (const float*)d_in[12];
    const float* b_d2 = (const float*)d_in[13];
    float* out = (float*)d_out;

    const int BN = in_sizes[0] / 3;   // 32768
    const int E  = in_sizes[1] / 2;   // 524288
    const int Bb = BN / 4096;         // 8
    const int* src = knn;
    const int* dst = knn + E;

    size_t off = 0;
    auto alloc = [&](size_t bytes) -> void* {
        void* p = (char*)d_ws + off;
        off += (bytes + 255) & ~(size_t)255;
        return p;
    };
    unsigned short* hs1 = (unsigned short*)alloc((size_t)(BN + 1) * 64 * 2);
    unsigned short* hs2 = (unsigned short*)alloc((size_t)(BN + 1) * 128 * 2);
    unsigned short* Wp1 = (unsigned short*)alloc((size_t)16 * 64 * 8 * 2);
    unsigned short* Wp2 = (unsigned short*)alloc((size_t)128 * 64 * 8 * 2);
    unsigned int* menc = (unsigned int*)alloc((size_t)Bb * 512 * 4);
    float* lat    = (float*)alloc((size_t)Bb * 512 * 4);
    float* dinv   = (float*)alloc((size_t)BN * 4);
    int*   cnt    = (int*)alloc((size_t)BN * 4);
    int*   pcnt   = (int*)alloc((size_t)BN * 4);
    int*   ssrc   = (int*)alloc((size_t)BN * 64 * 4);
    (void)ws_size;

    // prep: zero cnt + sentinel rows + m_enc, pack both weight matrices
    prep_kernel<<<273, 256, 0, stream>>>(
        cnt, (unsigned int*)(hs1 + (size_t)BN * 64),
        (unsigned int*)(hs2 + (size_t)BN * 128), menc, w_g1, Wp1, w_g2, Wp2);
    // count + direct scatter (slot known at atomicAdd time)
    count_scatter_kernel<<<(E + 255) / 256, 256, 0, stream>>>(src, dst, cnt, ssrc, E);
    // dinv + padded counts + sentinel pad-fill + cov/encoder (fused)
    padfill_cov_kernel<<<BN / 128, 128, 0, stream>>>(
        cnt, dinv, pcnt, ssrc, BN, x, w_e1, b_e1, hs1);

    // GCN1 fused: gather(64) -> MFMA K=64 -> bf16 hs2 (prescaled); M=64
    agg_gemm1_kernel<<<BN / 64, 256, 0, stream>>>(hs1, dinv, pcnt, ssrc, Wp1, b_g1, hs2);

    // GCN2 fused: gather(128) -> MFMA K=128 N=512 + column max; M=64
    agg_gemm2_kernel<<<BN / 64, 256, 0, stream>>>(hs2, dinv, pcnt, ssrc, Wp2, b_g2, menc);

    // latent matmul, parallel over 8x16 blocks
    lat_kernel<<<dim3(Bb, 16), 256, 0, stream>>>(menc, w_e2, b_e2, lat);

    // latw + decode (64 blocks: 8 batches x 8 slices)
    latw_decode_kernel<<<Bb * 8, 256, 0, stream>>>(lat, w_d1, b_d1, w_d2, b_d2, out);
}

// Round 10
// 191.026 us; speedup vs baseline: 1.0330x; 1.0330x over previous
//
#include <hip/hip_runtime.h>
#include <math.h>

#define SELU_SCALE 1.0507009873554804934193349852946f
#define SELU_ALPHA 1.6732632423543772848170429916717f

typedef short bf16x8 __attribute__((ext_vector_type(8)));
typedef float f32x4 __attribute__((ext_vector_type(4)));

__device__ __forceinline__ float selu_f(float x) {
    return SELU_SCALE * (x > 0.f ? x : SELU_ALPHA * expm1f(x));
}

__device__ __forceinline__ unsigned short f2bf(float f) {
    unsigned int u = __float_as_uint(f);
    u += 0x7FFF + ((u >> 16) & 1);  // round-to-nearest-even
    return (unsigned short)(u >> 16);
}
__device__ __forceinline__ float bflo(unsigned int u) { return __uint_as_float(u << 16); }
__device__ __forceinline__ float bfhi(unsigned int u) { return __uint_as_float(u & 0xFFFF0000u); }

// monotonic float<->uint encoding (order-preserving); max in uint == max in float
__device__ __forceinline__ unsigned int fenc(float f) {
    unsigned int u = __float_as_uint(f);
    return (u & 0x80000000u) ? ~u : (u | 0x80000000u);
}
__device__ __forceinline__ float fdec(unsigned int u) {
    return __uint_as_float((u & 0x80000000u) ? (u ^ 0x80000000u) : ~u);
}

__device__ __forceinline__ void acc8(float* a, uint4 v) {
    a[0] += bflo(v.x); a[1] += bfhi(v.x);
    a[2] += bflo(v.y); a[3] += bfhi(v.y);
    a[4] += bflo(v.z); a[5] += bfhi(v.z);
    a[6] += bflo(v.w); a[7] += bfhi(v.w);
}

__device__ __forceinline__ uint4 pack8(const float* a, float dv) {
    uint4 pk;
    pk.x = (unsigned int)f2bf(a[0] * dv) | ((unsigned int)f2bf(a[1] * dv) << 16);
    pk.y = (unsigned int)f2bf(a[2] * dv) | ((unsigned int)f2bf(a[3] * dv) << 16);
    pk.z = (unsigned int)f2bf(a[4] * dv) | ((unsigned int)f2bf(a[5] * dv) << 16);
    pk.w = (unsigned int)f2bf(a[6] * dv) | ((unsigned int)f2bf(a[7] * dv) << 16);
    return pk;
}

// 16-deep gather step: issues 16 independent uint4 loads (slot order j..j+15)
// then accumulates in the same sequential order as two 8-batches.
template <int TPN>
__device__ __forceinline__ void gather16(const uint4* hp, const int* sp, int j,
                                         int cq, float* a) {
    int4 sa = *(const int4*)&sp[j];
    int4 sb = *(const int4*)&sp[j + 4];
    int4 sc = *(const int4*)&sp[j + 8];
    int4 sd = *(const int4*)&sp[j + 12];
    uint4 v0 = hp[(size_t)sa.x * TPN + cq];
    uint4 v1 = hp[(size_t)sa.y * TPN + cq];
    uint4 v2 = hp[(size_t)sa.z * TPN + cq];
    uint4 v3 = hp[(size_t)sa.w * TPN + cq];
    uint4 v4 = hp[(size_t)sb.x * TPN + cq];
    uint4 v5 = hp[(size_t)sb.y * TPN + cq];
    uint4 v6 = hp[(size_t)sb.z * TPN + cq];
    uint4 v7 = hp[(size_t)sb.w * TPN + cq];
    uint4 v8 = hp[(size_t)sc.x * TPN + cq];
    uint4 v9 = hp[(size_t)sc.y * TPN + cq];
    uint4 va = hp[(size_t)sc.z * TPN + cq];
    uint4 vb = hp[(size_t)sc.w * TPN + cq];
    uint4 vc = hp[(size_t)sd.x * TPN + cq];
    uint4 vd = hp[(size_t)sd.y * TPN + cq];
    uint4 ve = hp[(size_t)sd.z * TPN + cq];
    uint4 vf = hp[(size_t)sd.w * TPN + cq];
    acc8(a, v0); acc8(a, v1); acc8(a, v2); acc8(a, v3);
    acc8(a, v4); acc8(a, v5); acc8(a, v6); acc8(a, v7);
    acc8(a, v8); acc8(a, v9); acc8(a, va); acc8(a, vb);
    acc8(a, vc); acc8(a, vd); acc8(a, ve); acc8(a, vf);
}

template <int TPN>
__device__ __forceinline__ void gather8(const uint4* hp, const int* sp, int j,
                                        int cq, float* a) {
    int4 sa = *(const int4*)&sp[j];
    int4 sb = *(const int4*)&sp[j + 4];
    uint4 v0 = hp[(size_t)sa.x * TPN + cq];
    uint4 v1 = hp[(size_t)sa.y * TPN + cq];
    uint4 v2 = hp[(size_t)sa.z * TPN + cq];
    uint4 v3 = hp[(size_t)sa.w * TPN + cq];
    uint4 v4 = hp[(size_t)sb.x * TPN + cq];
    uint4 v5 = hp[(size_t)sb.y * TPN + cq];
    uint4 v6 = hp[(size_t)sb.z * TPN + cq];
    uint4 v7 = hp[(size_t)sb.w * TPN + cq];
    acc8(a, v0); acc8(a, v1); acc8(a, v2); acc8(a, v3);
    acc8(a, v4); acc8(a, v5); acc8(a, v6); acc8(a, v7);
}

// ---------------------------------------------------------------------------
// prep: blocks 0..127 zero cnt; block 128 zeros sentinel rows + m_enc;
// blocks 129..272 pack weights into MFMA B-fragment layout.
// ---------------------------------------------------------------------------
__global__ __launch_bounds__(256) void prep_kernel(
    int* __restrict__ cnt, unsigned int* __restrict__ pad1,
    unsigned int* __restrict__ pad2, unsigned int* __restrict__ menc,
    const float* __restrict__ W1, unsigned short* __restrict__ Wp1,
    const float* __restrict__ W2, unsigned short* __restrict__ Wp2) {
    int b = blockIdx.x;
    int t = threadIdx.x;
    if (b < 128) {
        cnt[b * 256 + t] = 0;
    } else if (b == 128) {
        if (t < 32) pad1[t] = 0;   // hs1 sentinel row (64 bf16)
        if (t < 64) pad2[t] = 0;   // hs2 sentinel row (128 bf16)
        for (int i = t; i < 4096; i += 256) menc[i] = 0u;  // enc-min
    } else {
        if (t >= 64) return;
        int fb = b - 129;
        const float* W; unsigned short* Wp; int K, N, f;
        if (fb < 16) { W = W1; Wp = Wp1; K = 64; N = 128; f = fb; }
        else         { W = W2; Wp = Wp2; K = 128; N = 512; f = fb - 16; }
        int l = t;  // 0..63
        int KS = K / 32;
        int nt = f / KS, ks = f % KS;
        int ncol = nt * 16 + (l & 15);
        int k0 = ks * 32 + (l >> 4) * 8;
        unsigned short v[8];
        #pragma unroll
        for (int j = 0; j < 8; j++) v[j] = f2bf(W[(size_t)(k0 + j) * N + ncol]);
        *(uint4*)&Wp[((size_t)f * 64 + l) * 8] = *(uint4*)v;
    }
}

// ---------------------------------------------------------------------------
// count + scatter, 2 edges/thread via int2 loads (atomics unchanged; edge
// ordering is nondeterministic by construction, same as before).
// ---------------------------------------------------------------------------
__global__ __launch_bounds__(256) void count_scatter_kernel(
    const int* __restrict__ src, const int* __restrict__ dst,
    int* __restrict__ cnt, int* __restrict__ ssrc, int E) {
    int e = (blockIdx.x * 256 + threadIdx.x) * 2;
    if (e >= E) return;
    int2 d2 = *(const int2*)&dst[e];
    int2 s2 = *(const int2*)&src[e];
    int pos0 = atomicAdd(&cnt[d2.x], 1);
    if (pos0 < 64) ssrc[((size_t)d2.x << 6) + pos0] = s2.x;
    int pos1 = atomicAdd(&cnt[d2.y], 1);
    if (pos1 < 64) ssrc[((size_t)d2.y << 6) + pos1] = s2.y;
}

// ---------------------------------------------------------------------------
// padfill + cov/encoder fused (verified r4).  256 blocks x 128 threads.
// ---------------------------------------------------------------------------
__global__ __launch_bounds__(128) void padfill_cov_kernel(
    const int* __restrict__ cnt, float* __restrict__ dinv,
    int* __restrict__ pcnt, int* __restrict__ ssrc, int n,
    const float* __restrict__ x, const float* __restrict__ w_e1,
    const float* __restrict__ b_e1, unsigned short* __restrict__ hs1) {
    __shared__ float Wl[12 * 64];
    __shared__ float Bl[64];
    __shared__ float xs[152 * 3];
    int t = threadIdx.x;
    int p0 = blockIdx.x * 128;
    int p = p0 + t;

    // ---- padfill part (in-register dinv) ----
    int c = cnt[p];
    float dv = rsqrtf((float)(c + 1));
    dinv[p] = dv;
    int pc = (c + 7) & ~7;
    if (pc > 64) pc = 64;
    pcnt[p] = pc;
    {
        int* row = ssrc + ((size_t)p << 6);
        for (int k = c; k < pc; k++) row[k] = n;  // sentinel zero-row
    }

    // ---- cov + encoder part ----
    for (int i = t; i < 768; i += 128) Wl[i] = w_e1[i];
    if (t < 64) Bl[t] = b_e1[t];
    int n0 = p0 & 4095;
    const float* xb = x + (size_t)(p0 - n0) * 3;  // batch base (128 | 4096)
    for (int idx = t; idx < 456; idx += 128) {    // (128+24) slots x 3
        int slot = idx / 3, d = idx - slot * 3;
        int g = n0 - 12 + slot;
        g = g < 0 ? 0 : (g > 4095 ? 4095 : g);
        xs[idx] = xb[g * 3 + d];
    }
    __syncthreads();
    int nn = n0 + t;
    int lo = nn - 12 < 0 ? 0 : nn - 12;
    int hi = nn + 12 > 4095 ? 4095 : nn + 12;
    int slo = lo - n0 + 12, shi = hi - n0 + 12;
    float sx = 0.f, sy = 0.f, sz = 0.f;
    float sxx = 0.f, sxy = 0.f, sxz = 0.f, syy = 0.f, syz = 0.f, szz = 0.f;
    for (int s = slo; s <= shi; s++) {
        float xv = xs[s * 3 + 0], yv = xs[s * 3 + 1], zv = xs[s * 3 + 2];
        sx += xv; sy += yv; sz += zv;
        sxx = fmaf(xv, xv, sxx); sxy = fmaf(xv, yv, sxy); sxz = fmaf(xv, zv, sxz);
        syy = fmaf(yv, yv, syy); syz = fmaf(yv, zv, syz); szz = fmaf(zv, zv, szz);
    }
    float cntf = (float)(shi - slo + 1);
    float rin = 1.f / cntf;
    float mx = sx * rin, my = sy * rin, mz = sz * rin;
    const float inv23 = 1.f / 23.f;
    float c00 = (sxx - sx * mx) * inv23;
    float c01 = (sxy - sx * my) * inv23;
    float c02 = (sxz - sx * mz) * inv23;
    float c11 = (syy - sy * my) * inv23;
    float c12 = (syz - sy * mz) * inv23;
    float c22 = (szz - sz * mz) * inv23;
    float feat[12];
    feat[0] = xs[(t + 12) * 3 + 0];
    feat[1] = xs[(t + 12) * 3 + 1];
    feat[2] = xs[(t + 12) * 3 + 2];
    feat[3] = c00; feat[4] = c01; feat[5]  = c02;
    feat[6] = c01; feat[7] = c11; feat[8]  = c12;
    feat[9] = c02; feat[10] = c12; feat[11] = c22;
    unsigned int* hp = (unsigned int*)(hs1 + (size_t)p * 64);
    for (int cc = 0; cc < 64; cc += 2) {
        float a0 = Bl[cc], a1 = Bl[cc + 1];
        #pragma unroll
        for (int i = 0; i < 12; i++) {
            a0 = fmaf(feat[i], Wl[i * 64 + cc], a0);
            a1 = fmaf(feat[i], Wl[i * 64 + cc + 1], a1);
        }
        unsigned int pk = (unsigned int)f2bf(dv * selu_f(a0)) |
                          ((unsigned int)f2bf(dv * selu_f(a1)) << 16);
        hp[cc >> 1] = pk;
    }
}

// ---------------------------------------------------------------------------
// GCN1 fused (verified r6): gather(64ch, 16-deep) into LDS, MFMA K=64 N=128.
// ---------------------------------------------------------------------------
__global__ __launch_bounds__(256) void agg_gemm1_kernel(
    const unsigned short* __restrict__ hs, const float* __restrict__ dinv,
    const int* __restrict__ pcnt, const int* __restrict__ ssrc,
    const unsigned short* __restrict__ Wp, const float* __restrict__ bias,
    unsigned short* __restrict__ hs2) {
    constexpr int LDA = 72;  // 64 + 8 bf16 pad
    __shared__ unsigned short As[64 * LDA];
    int t = threadIdx.x;
    int R0 = blockIdx.x * 64;
    const uint4* hp = (const uint4*)hs;

    // ---- gather phase: TPN=8, 32 nodes per pass, 2 passes ----
    #pragma unroll
    for (int pass = 0; pass < 2; pass++) {
        int rloc = pass * 32 + (t >> 3);
        int node = R0 + rloc;
        int cq = t & 7;
        float a[8];
        {
            uint4 u = hp[(size_t)node * 8 + cq];
            a[0] = bflo(u.x); a[1] = bfhi(u.x);
            a[2] = bflo(u.y); a[3] = bfhi(u.y);
            a[4] = bflo(u.z); a[5] = bfhi(u.z);
            a[6] = bflo(u.w); a[7] = bfhi(u.w);
        }
        int pc = pcnt[node];
        const int* sp = ssrc + ((size_t)node << 6);
        int j = 0;
        for (; j + 16 <= pc; j += 16) gather16<8>(hp, sp, j, cq, a);
        if (j < pc) gather8<8>(hp, sp, j, cq, a);
        *(uint4*)&As[rloc * LDA + cq * 8] = pack8(a, dinv[node]);
    }
    __syncthreads();

    // ---- MFMA phase: 4 waves x 16 rows ----
    int wave = t >> 6, l = t & 63;
    int ml = l & 15, q = l >> 4;
    int wr = wave * 16;
    f32x4 acc[8];
    #pragma unroll
    for (int nf = 0; nf < 8; nf++) acc[nf] = (f32x4){0.f, 0.f, 0.f, 0.f};
    const bf16x8* wp8 = (const bf16x8*)Wp;
    #pragma unroll
    for (int ks = 0; ks < 2; ks++) {
        bf16x8 af = *(const bf16x8*)&As[(wr + ml) * LDA + ks * 32 + q * 8];
        bf16x8 bfr[8];
        #pragma unroll
        for (int nf = 0; nf < 8; nf++)
            bfr[nf] = wp8[(size_t)(nf * 2 + ks) * 64 + l];
        #pragma unroll
        for (int nf = 0; nf < 8; nf++)
            acc[nf] = __builtin_amdgcn_mfma_f32_16x16x32_bf16(
                af, bfr[nf], acc[nf], 0, 0, 0);
    }
    float bj[8];
    #pragma unroll
    for (int nf = 0; nf < 8; nf++) bj[nf] = bias[nf * 16 + ml];
    #pragma unroll
    for (int r = 0; r < 4; r++) {
        int row = R0 + wr + q * 4 + r;
        float dv = dinv[row];
        #pragma unroll
        for (int nf = 0; nf < 8; nf++) {
            float v = dv * selu_f(acc[nf][r] + bj[nf]);
            hs2[(size_t)row * 128 + nf * 16 + ml] = f2bf(v);
        }
    }
}

// ---------------------------------------------------------------------------
// GCN2 fused (verified r6 form): gather(128ch, 16-deep) into LDS once, loop
// 4 column-blocks of the K=128 N=512 MFMA + column max -> atomicMax (exact).
// ---------------------------------------------------------------------------
__global__ __launch_bounds__(256) void agg_gemm2_kernel(
    const unsigned short* __restrict__ hs, const float* __restrict__ dinv,
    const int* __restrict__ pcnt, const int* __restrict__ ssrc,
    const unsigned short* __restrict__ Wp, const float* __restrict__ bias,
    unsigned int* __restrict__ menc) {
    constexpr int KS = 4;
    constexpr int LDA = 136;  // 128 + 8
    __shared__ unsigned short As[64 * LDA];
    __shared__ float redf[4 * 128];
    int t = threadIdx.x;
    int R0 = blockIdx.x * 64;
    const uint4* hp = (const uint4*)hs;

    // ---- gather phase: TPN=16, 16 nodes per pass, 4 passes ----
    #pragma unroll
    for (int pass = 0; pass < 4; pass++) {
        int rloc = pass * 16 + (t >> 4);
        int node = R0 + rloc;
        int cq = t & 15;
        float a[8];
        {
            uint4 u = hp[(size_t)node * 16 + cq];
            a[0] = bflo(u.x); a[1] = bfhi(u.x);
            a[2] = bflo(u.y); a[3] = bfhi(u.y);
            a[4] = bflo(u.z); a[5] = bfhi(u.z);
            a[6] = bflo(u.w); a[7] = bfhi(u.w);
        }
        int pc = pcnt[node];
        const int* sp = ssrc + ((size_t)node << 6);
        int j = 0;
        for (; j + 16 <= pc; j += 16) gather16<16>(hp, sp, j, cq, a);
        if (j < pc) gather8<16>(hp, sp, j, cq, a);
        *(uint4*)&As[rloc * LDA + cq * 8] = pack8(a, dinv[node]);
    }
    __syncthreads();

    // ---- MFMA phase: 4 waves x 16 rows, loop over 4 column-blocks ----
    int wave = t >> 6, l = t & 63;
    int ml = l & 15, q = l >> 4;
    int wr = wave * 16;
    int b = blockIdx.x >> 6;  // 64 row-tiles per batch
    const bf16x8* wp8 = (const bf16x8*)Wp;
    for (int cbi = 0; cbi < 4; cbi++) {
        f32x4 acc[8];
        #pragma unroll
        for (int nf = 0; nf < 8; nf++) acc[nf] = (f32x4){0.f, 0.f, 0.f, 0.f};
        #pragma unroll
        for (int ks = 0; ks < KS; ks++) {
            bf16x8 af = *(const bf16x8*)&As[(wr + ml) * LDA + ks * 32 + q * 8];
            bf16x8 bfr[8];
            #pragma unroll
            for (int nf = 0; nf < 8; nf++)
                bfr[nf] = wp8[(size_t)((cbi * 8 + nf) * KS + ks) * 64 + l];
            #pragma unroll
            for (int nf = 0; nf < 8; nf++)
                acc[nf] = __builtin_amdgcn_mfma_f32_16x16x32_bf16(
                    af, bfr[nf], acc[nf], 0, 0, 0);
        }
        // selu + column max; C/D layout: col = ml, row = q*4 + r
        float cmax[8];
        #pragma unroll
        for (int nf = 0; nf < 8; nf++) {
            float bj = bias[cbi * 128 + nf * 16 + ml];
            float v = -INFINITY;
            #pragma unroll
            for (int r = 0; r < 4; r++)
                v = fmaxf(v, selu_f(acc[nf][r] + bj));
            v = fmaxf(v, __shfl_xor(v, 16, 64));
            v = fmaxf(v, __shfl_xor(v, 32, 64));
            cmax[nf] = v;
        }
        __syncthreads();  // redf free (prev cbi readers done)
        if (ml == l) {  // lanes 0..15
            #pragma unroll
            for (int nf = 0; nf < 8; nf++) redf[wave * 128 + nf * 16 + l] = cmax[nf];
        }
        __syncthreads();
        if (t < 128) {
            float v = redf[t];
            v = fmaxf(v, redf[128 + t]);
            v = fmaxf(v, redf[256 + t]);
            v = fmaxf(v, redf[384 + t]);
            atomicMax(&menc[b * 512 + cbi * 128 + t], fenc(v));
        }
    }
}

// ---------------------------------------------------------------------------
// lat: grid (8 batches, 16 col-groups of 32).  lat[b][c] =
// selu(sum_k m[b][k]*w_e2[k][c] + b_e2[c]).  k split 8 ways, LDS reduce.
// ---------------------------------------------------------------------------
__global__ __launch_bounds__(256) void lat_kernel(
    const unsigned int* __restrict__ menc, const float* __restrict__ w_e2,
    const float* __restrict__ b_e2, float* __restrict__ lat) {
    int b = blockIdx.x;
    int cg = blockIdx.y;
    int t = threadIdx.x;
    __shared__ float ml[512];
    __shared__ float red[8][32];
    ml[t] = fdec(menc[b * 512 + t]);
    ml[t + 256] = fdec(menc[b * 512 + t + 256]);
    __syncthreads();
    int cl = t & 31;          // column within group
    int kg = t >> 5;          // 0..7, k-chunks of 64
    int c = cg * 32 + cl;
    const float* wp = w_e2 + (size_t)(kg * 64) * 512 + c;
    const float* mlp = ml + kg * 64;
    float acc = 0.f;
    #pragma unroll 16
    for (int k = 0; k < 64; k++) acc = fmaf(mlp[k], wp[(size_t)k * 512], acc);
    red[kg][cl] = acc;
    __syncthreads();
    if (t < 32) {
        float v = ((red[0][t] + red[1][t]) + (red[2][t] + red[3][t])) +
                  ((red[4][t] + red[5][t]) + (red[6][t] + red[7][t]));
        lat[b * 512 + cg * 32 + t] = selu_f(v + b_e2[cg * 32 + t]);
    }
}

// ---------------------------------------------------------------------------
// latw + decode: 64 blocks = 8 batches x 8 point-slices.  Each block
// recomputes the tiny latw reduction (512x6) then decodes its 512 points.
// ---------------------------------------------------------------------------
__global__ __launch_bounds__(256) void latw_decode_kernel(
    const float* __restrict__ lat, const float* __restrict__ w_d1,
    const float* __restrict__ b_d1, const float* __restrict__ w_d2,
    const float* __restrict__ b_d2, float* __restrict__ out) {
    int b = blockIdx.x >> 3;   // batch
    int sl = blockIdx.x & 7;   // point slice
    int t = threadIdx.x;
    __shared__ float ll[512];
    __shared__ float red[6][256];
    __shared__ float lw[6];
    ll[t] = lat[b * 512 + t];
    ll[t + 256] = lat[b * 512 + t + 256];
    __syncthreads();
    float p[6] = {0.f, 0.f, 0.f, 0.f, 0.f, 0.f};
    for (int k = t; k < 512; k += 256) {
        float lv = ll[k];
        #pragma unroll
        for (int j = 0; j < 3; j++) {
            p[j]     = fmaf(lv, w_d1[k * 3 + j], p[j]);
            p[3 + j] = fmaf(lv, w_d2[k * 3 + j], p[3 + j]);
        }
    }
    #pragma unroll
    for (int j = 0; j < 6; j++) red[j][t] = p[j];
    __syncthreads();
    for (int s = 128; s > 0; s >>= 1) {
        if (t < s) {
            #pragma unroll
            for (int j = 0; j < 6; j++) red[j][t] += red[j][t + s];
        }
        __syncthreads();
    }
    if (t < 3) {
        lw[t]     = red[t][0] + b_d1[t];
        lw[3 + t] = red[3 + t][0] + b_d2[t];
    }
    __syncthreads();
    float l10 = lw[0], l11 = lw[1], l12 = lw[2];
    float l20 = lw[3], l21 = lw[4], l22 = lw[5];
    float w1a0 = w_d1[1536 + 0], w1a1 = w_d1[1536 + 1], w1a2 = w_d1[1536 + 2];
    float w1b0 = w_d1[1539 + 0], w1b1 = w_d1[1539 + 1], w1b2 = w_d1[1539 + 2];
    float w2a0 = w_d2[1536 + 0], w2a1 = w_d2[1536 + 1], w2a2 = w_d2[1536 + 2];
    float w2b0 = w_d2[1539 + 0], w2b1 = w_d2[1539 + 1], w2b2 = w_d2[1539 + 2];
    float w2c0 = w_d2[1542 + 0], w2c1 = w_d2[1542 + 1], w2c2 = w_d2[1542 + 2];
    {
        int n = sl * 512 + t;
        #pragma unroll
        for (int half = 0; half < 2; half++) {
            int i = n / 46;
            int j = n - i * 46;
            float y0 = fmaf((float)i, 119.f / 90.f, 1.f);
            float y1 = fmaf((float)j, 59.f / 45.f, 1.f);
            float k0 = selu_f(l10 + y0 * w1a0 + y1 * w1b0);
            float k1 = selu_f(l11 + y0 * w1a1 + y1 * w1b1);
            float k2 = selu_f(l12 + y0 * w1a2 + y1 * w1b2);
            float o0 = selu_f(l20 + k0 * w2a0 + k1 * w2b0 + k2 * w2c0);
            float o1 = selu_f(l21 + k0 * w2a1 + k1 * w2b1 + k2 * w2c1);
            float o2 = selu_f(l22 + k0 * w2a2 + k1 * w2b2 + k2 * w2c2);
            size_t pidx = (size_t)(b * 4096 + n) * 3;
            out[pidx + 0] = o0;
            out[pidx + 1] = o1;
            out[pidx + 2] = o2;
            n += 256;
        }
    }
}

// ---------------------------------------------------------------------------
extern "C" void kernel_launch(void* const* d_in, const int* in_sizes, int n_in,
                              void* d_out, int out_size, void* d_ws, size_t ws_size,
                              hipStream_t stream) {
    const float* x    = (const float*)d_in[0];
    const int*   knn  = (const int*)d_in[1];
    const float* w_e1 = (const float*)d_in[2];
    const float* b_e1 = (const float*)d_in[3];
    const float* w_g1 = (const float*)d_in[4];
    const float* b_g1 = (const float*)d_in[5];
    const float* w_g2 = (const float*)d_in[6];
    const float* b_g2 = (const float*)d_in[7];
    const float* w_e2 = (const float*)d_in[8];
    const float* b_e2 = (const float*)d_in[9];
    const float* w_d1 = (const float*)d_in[10];
    const float* b_d1 = (const float*)d_in[11];
    const float* w_d2 = (const float*)d_in[12];
    const float* b_d2 = (const float*)d_in[13];
    float* out = (float*)d_out;

    const int BN = in_sizes[0] / 3;   // 32768
    const int E  = in_sizes[1] / 2;   // 524288
    const int Bb = BN / 4096;         // 8
    const int* src = knn;
    const int* dst = knn + E;

    size_t off = 0;
    auto alloc = [&](size_t bytes) -> void* {
        void* p = (char*)d_ws + off;
        off += (bytes + 255) & ~(size_t)255;
        return p;
    };
    unsigned short* hs1 = (unsigned short*)alloc((size_t)(BN + 1) * 64 * 2);
    unsigned short* hs2 = (unsigned short*)alloc((size_t)(BN + 1) * 128 * 2);
    unsigned short* Wp1 = (unsigned short*)alloc((size_t)16 * 64 * 8 * 2);
    unsigned short* Wp2 = (unsigned short*)alloc((size_t)128 * 64 * 8 * 2);
    unsigned int* menc = (unsigned int*)alloc((size_t)Bb * 512 * 4);
    float* lat    = (float*)alloc((size_t)Bb * 512 * 4);
    float* dinv   = (float*)alloc((size_t)BN * 4);
    int*   cnt    = (int*)alloc((size_t)BN * 4);
    int*   pcnt   = (int*)alloc((size_t)BN * 4);
    int*   ssrc   = (int*)alloc((size_t)BN * 64 * 4);
    (void)ws_size;

    // prep: zero cnt + sentinel rows + m_enc, pack both weight matrices
    prep_kernel<<<273, 256, 0, stream>>>(
        cnt, (unsigned int*)(hs1 + (size_t)BN * 64),
        (unsigned int*)(hs2 + (size_t)BN * 128), menc, w_g1, Wp1, w_g2, Wp2);
    // count + direct scatter, 2 edges/thread
    count_scatter_kernel<<<(E / 2 + 255) / 256, 256, 0, stream>>>(src, dst, cnt, ssrc, E);
    // dinv + padded counts + sentinel pad-fill + cov/encoder (fused)
    padfill_cov_kernel<<<BN / 128, 128, 0, stream>>>(
        cnt, dinv, pcnt, ssrc, BN, x, w_e1, b_e1, hs1);

    // GCN1 fused: gather(64) -> MFMA K=64 -> bf16 hs2 (prescaled); M=64
    agg_gemm1_kernel<<<BN / 64, 256, 0, stream>>>(hs1, dinv, pcnt, ssrc, Wp1, b_g1, hs2);

    // GCN2 fused: gather(128) -> MFMA K=128 N=512 + column max; M=64
    agg_gemm2_kernel<<<BN / 64, 256, 0, stream>>>(hs2, dinv, pcnt, ssrc, Wp2, b_g2, menc);

    // latent matmul, parallel over 8x16 blocks
    lat_kernel<<<dim3(Bb, 16), 256, 0, stream>>>(menc, w_e2, b_e2, lat);

    // latw + decode (64 blocks: 8 batches x 8 slices)
    latw_decode_kernel<<<Bb * 8, 256, 0, stream>>>(lat, w_d1, b_d1, w_d2, b_d2, out);
}

// Round 11
// 190.379 us; speedup vs baseline: 1.0365x; 1.0034x over previous
//
#include <hip/hip_runtime.h>
#include <math.h>

#define SELU_SCALE 1.0507009873554804934193349852946f
#define SELU_ALPHA 1.6732632423543772848170429916717f

typedef short bf16x8 __attribute__((ext_vector_type(8)));
typedef float f32x4 __attribute__((ext_vector_type(4)));

__device__ __forceinline__ float selu_f(float x) {
    return SELU_SCALE * (x > 0.f ? x : SELU_ALPHA * expm1f(x));
}

__device__ __forceinline__ unsigned short f2bf(float f) {
    unsigned int u = __float_as_uint(f);
    u += 0x7FFF + ((u >> 16) & 1);  // round-to-nearest-even
    return (unsigned short)(u >> 16);
}
__device__ __forceinline__ float bflo(unsigned int u) { return __uint_as_float(u << 16); }
__device__ __forceinline__ float bfhi(unsigned int u) { return __uint_as_float(u & 0xFFFF0000u); }

// monotonic float<->uint encoding (order-preserving); max in uint == max in float
__device__ __forceinline__ unsigned int fenc(float f) {
    unsigned int u = __float_as_uint(f);
    return (u & 0x80000000u) ? ~u : (u | 0x80000000u);
}
__device__ __forceinline__ float fdec(unsigned int u) {
    return __uint_as_float((u & 0x80000000u) ? (u ^ 0x80000000u) : ~u);
}

__device__ __forceinline__ void acc8(float* a, uint4 v) {
    a[0] += bflo(v.x); a[1] += bfhi(v.x);
    a[2] += bflo(v.y); a[3] += bfhi(v.y);
    a[4] += bflo(v.z); a[5] += bfhi(v.z);
    a[6] += bflo(v.w); a[7] += bfhi(v.w);
}

__device__ __forceinline__ uint4 pack8(const float* a, float dv) {
    uint4 pk;
    pk.x = (unsigned int)f2bf(a[0] * dv) | ((unsigned int)f2bf(a[1] * dv) << 16);
    pk.y = (unsigned int)f2bf(a[2] * dv) | ((unsigned int)f2bf(a[3] * dv) << 16);
    pk.z = (unsigned int)f2bf(a[4] * dv) | ((unsigned int)f2bf(a[5] * dv) << 16);
    pk.w = (unsigned int)f2bf(a[6] * dv) | ((unsigned int)f2bf(a[7] * dv) << 16);
    return pk;
}

// 16-deep gather step: issues 16 independent uint4 loads (slot order j..j+15)
// then accumulates in the same sequential order as two 8-batches.
template <int TPN>
__device__ __forceinline__ void gather16(const uint4* hp, const int* sp, int j,
                                         int cq, float* a) {
    int4 sa = *(const int4*)&sp[j];
    int4 sb = *(const int4*)&sp[j + 4];
    int4 sc = *(const int4*)&sp[j + 8];
    int4 sd = *(const int4*)&sp[j + 12];
    uint4 v0 = hp[(size_t)sa.x * TPN + cq];
    uint4 v1 = hp[(size_t)sa.y * TPN + cq];
    uint4 v2 = hp[(size_t)sa.z * TPN + cq];
    uint4 v3 = hp[(size_t)sa.w * TPN + cq];
    uint4 v4 = hp[(size_t)sb.x * TPN + cq];
    uint4 v5 = hp[(size_t)sb.y * TPN + cq];
    uint4 v6 = hp[(size_t)sb.z * TPN + cq];
    uint4 v7 = hp[(size_t)sb.w * TPN + cq];
    uint4 v8 = hp[(size_t)sc.x * TPN + cq];
    uint4 v9 = hp[(size_t)sc.y * TPN + cq];
    uint4 va = hp[(size_t)sc.z * TPN + cq];
    uint4 vb = hp[(size_t)sc.w * TPN + cq];
    uint4 vc = hp[(size_t)sd.x * TPN + cq];
    uint4 vd = hp[(size_t)sd.y * TPN + cq];
    uint4 ve = hp[(size_t)sd.z * TPN + cq];
    uint4 vf = hp[(size_t)sd.w * TPN + cq];
    acc8(a, v0); acc8(a, v1); acc8(a, v2); acc8(a, v3);
    acc8(a, v4); acc8(a, v5); acc8(a, v6); acc8(a, v7);
    acc8(a, v8); acc8(a, v9); acc8(a, va); acc8(a, vb);
    acc8(a, vc); acc8(a, vd); acc8(a, ve); acc8(a, vf);
}

template <int TPN>
__device__ __forceinline__ void gather8(const uint4* hp, const int* sp, int j,
                                        int cq, float* a) {
    int4 sa = *(const int4*)&sp[j];
    int4 sb = *(const int4*)&sp[j + 4];
    uint4 v0 = hp[(size_t)sa.x * TPN + cq];
    uint4 v1 = hp[(size_t)sa.y * TPN + cq];
    uint4 v2 = hp[(size_t)sa.z * TPN + cq];
    uint4 v3 = hp[(size_t)sa.w * TPN + cq];
    uint4 v4 = hp[(size_t)sb.x * TPN + cq];
    uint4 v5 = hp[(size_t)sb.y * TPN + cq];
    uint4 v6 = hp[(size_t)sb.z * TPN + cq];
    uint4 v7 = hp[(size_t)sb.w * TPN + cq];
    acc8(a, v0); acc8(a, v1); acc8(a, v2); acc8(a, v3);
    acc8(a, v4); acc8(a, v5); acc8(a, v6); acc8(a, v7);
}

// ---------------------------------------------------------------------------
// prep: blocks 0..127 zero cnt; block 128 zeros sentinel rows + m_enc;
// blocks 129..272 pack weights into MFMA B-fragment layout.
// ---------------------------------------------------------------------------
__global__ __launch_bounds__(256) void prep_kernel(
    int* __restrict__ cnt, unsigned int* __restrict__ pad1,
    unsigned int* __restrict__ pad2, unsigned int* __restrict__ menc,
    const float* __restrict__ W1, unsigned short* __restrict__ Wp1,
    const float* __restrict__ W2, unsigned short* __restrict__ Wp2) {
    int b = blockIdx.x;
    int t = threadIdx.x;
    if (b < 128) {
        cnt[b * 256 + t] = 0;
    } else if (b == 128) {
        if (t < 32) pad1[t] = 0;   // hs1 sentinel row (64 bf16)
        if (t < 64) pad2[t] = 0;   // hs2 sentinel row (128 bf16)
        for (int i = t; i < 4096; i += 256) menc[i] = 0u;  // enc-min
    } else {
        if (t >= 64) return;
        int fb = b - 129;
        const float* W; unsigned short* Wp; int K, N, f;
        if (fb < 16) { W = W1; Wp = Wp1; K = 64; N = 128; f = fb; }
        else         { W = W2; Wp = Wp2; K = 128; N = 512; f = fb - 16; }
        int l = t;  // 0..63
        int KS = K / 32;
        int nt = f / KS, ks = f % KS;
        int ncol = nt * 16 + (l & 15);
        int k0 = ks * 32 + (l >> 4) * 8;
        unsigned short v[8];
        #pragma unroll
        for (int j = 0; j < 8; j++) v[j] = f2bf(W[(size_t)(k0 + j) * N + ncol]);
        *(uint4*)&Wp[((size_t)f * 64 + l) * 8] = *(uint4*)v;
    }
}

// ---------------------------------------------------------------------------
// count + scatter, 2 edges/thread via int2 loads (verified r10).
// ---------------------------------------------------------------------------
__global__ __launch_bounds__(256) void count_scatter_kernel(
    const int* __restrict__ src, const int* __restrict__ dst,
    int* __restrict__ cnt, int* __restrict__ ssrc, int E) {
    int e = (blockIdx.x * 256 + threadIdx.x) * 2;
    if (e >= E) return;
    int2 d2 = *(const int2*)&dst[e];
    int2 s2 = *(const int2*)&src[e];
    int pos0 = atomicAdd(&cnt[d2.x], 1);
    if (pos0 < 64) ssrc[((size_t)d2.x << 6) + pos0] = s2.x;
    int pos1 = atomicAdd(&cnt[d2.y], 1);
    if (pos1 < 64) ssrc[((size_t)d2.y << 6) + pos1] = s2.y;
}

// ---------------------------------------------------------------------------
// padfill + cov/encoder fused (verified r4).  256 blocks x 128 threads.
// Sentinel-fill now extends to >=24 slots so the gather's common path can be
// branch-free (slots pc..24 read the zero row: a += 0, value-exact).
// ---------------------------------------------------------------------------
__global__ __launch_bounds__(128) void padfill_cov_kernel(
    const int* __restrict__ cnt, float* __restrict__ dinv,
    int* __restrict__ pcnt, int* __restrict__ ssrc, int n,
    const float* __restrict__ x, const float* __restrict__ w_e1,
    const float* __restrict__ b_e1, unsigned short* __restrict__ hs1) {
    __shared__ float Wl[12 * 64];
    __shared__ float Bl[64];
    __shared__ float xs[152 * 3];
    int t = threadIdx.x;
    int p0 = blockIdx.x * 128;
    int p = p0 + t;

    // ---- padfill part (in-register dinv) ----
    int c = cnt[p];
    float dv = rsqrtf((float)(c + 1));
    dinv[p] = dv;
    int pc = (c + 7) & ~7;
    if (pc > 64) pc = 64;
    pcnt[p] = pc;
    {
        int fillto = pc < 24 ? 24 : pc;  // branch-free gather reads slots 0..23
        int* row = ssrc + ((size_t)p << 6);
        for (int k = c; k < fillto; k++) row[k] = n;  // sentinel zero-row
    }

    // ---- cov + encoder part ----
    for (int i = t; i < 768; i += 128) Wl[i] = w_e1[i];
    if (t < 64) Bl[t] = b_e1[t];
    int n0 = p0 & 4095;
    const float* xb = x + (size_t)(p0 - n0) * 3;  // batch base (128 | 4096)
    for (int idx = t; idx < 456; idx += 128) {    // (128+24) slots x 3
        int slot = idx / 3, d = idx - slot * 3;
        int g = n0 - 12 + slot;
        g = g < 0 ? 0 : (g > 4095 ? 4095 : g);
        xs[idx] = xb[g * 3 + d];
    }
    __syncthreads();
    int nn = n0 + t;
    int lo = nn - 12 < 0 ? 0 : nn - 12;
    int hi = nn + 12 > 4095 ? 4095 : nn + 12;
    int slo = lo - n0 + 12, shi = hi - n0 + 12;
    float sx = 0.f, sy = 0.f, sz = 0.f;
    float sxx = 0.f, sxy = 0.f, sxz = 0.f, syy = 0.f, syz = 0.f, szz = 0.f;
    for (int s = slo; s <= shi; s++) {
        float xv = xs[s * 3 + 0], yv = xs[s * 3 + 1], zv = xs[s * 3 + 2];
        sx += xv; sy += yv; sz += zv;
        sxx = fmaf(xv, xv, sxx); sxy = fmaf(xv, yv, sxy); sxz = fmaf(xv, zv, sxz);
        syy = fmaf(yv, yv, syy); syz = fmaf(yv, zv, syz); szz = fmaf(zv, zv, szz);
    }
    float cntf = (float)(shi - slo + 1);
    float rin = 1.f / cntf;
    float mx = sx * rin, my = sy * rin, mz = sz * rin;
    const float inv23 = 1.f / 23.f;
    float c00 = (sxx - sx * mx) * inv23;
    float c01 = (sxy - sx * my) * inv23;
    float c02 = (sxz - sx * mz) * inv23;
    float c11 = (syy - sy * my) * inv23;
    float c12 = (syz - sy * mz) * inv23;
    float c22 = (szz - sz * mz) * inv23;
    float feat[12];
    feat[0] = xs[(t + 12) * 3 + 0];
    feat[1] = xs[(t + 12) * 3 + 1];
    feat[2] = xs[(t + 12) * 3 + 2];
    feat[3] = c00; feat[4] = c01; feat[5]  = c02;
    feat[6] = c01; feat[7] = c11; feat[8]  = c12;
    feat[9] = c02; feat[10] = c12; feat[11] = c22;
    unsigned int* hp = (unsigned int*)(hs1 + (size_t)p * 64);
    for (int cc = 0; cc < 64; cc += 2) {
        float a0 = Bl[cc], a1 = Bl[cc + 1];
        #pragma unroll
        for (int i = 0; i < 12; i++) {
            a0 = fmaf(feat[i], Wl[i * 64 + cc], a0);
            a1 = fmaf(feat[i], Wl[i * 64 + cc + 1], a1);
        }
        unsigned int pk = (unsigned int)f2bf(dv * selu_f(a0)) |
                          ((unsigned int)f2bf(dv * selu_f(a1)) << 16);
        hp[cc >> 1] = pk;
    }
}

// ---------------------------------------------------------------------------
// GCN1 fused: gather(64ch) into LDS, MFMA K=64 N=128.  Gather common path is
// now branch-free (fixed 24 slots; sentinel-padded), rare tail for pc>24.
// ---------------------------------------------------------------------------
__global__ __launch_bounds__(256) void agg_gemm1_kernel(
    const unsigned short* __restrict__ hs, const float* __restrict__ dinv,
    const int* __restrict__ pcnt, const int* __restrict__ ssrc,
    const unsigned short* __restrict__ Wp, const float* __restrict__ bias,
    unsigned short* __restrict__ hs2) {
    constexpr int LDA = 72;  // 64 + 8 bf16 pad
    __shared__ unsigned short As[64 * LDA];
    int t = threadIdx.x;
    int R0 = blockIdx.x * 64;
    const uint4* hp = (const uint4*)hs;

    // ---- gather phase: TPN=8, 32 nodes per pass, 2 passes ----
    #pragma unroll
    for (int pass = 0; pass < 2; pass++) {
        int rloc = pass * 32 + (t >> 3);
        int node = R0 + rloc;
        int cq = t & 7;
        float a[8];
        {
            uint4 u = hp[(size_t)node * 8 + cq];
            a[0] = bflo(u.x); a[1] = bfhi(u.x);
            a[2] = bflo(u.y); a[3] = bfhi(u.y);
            a[4] = bflo(u.z); a[5] = bfhi(u.z);
            a[6] = bflo(u.w); a[7] = bfhi(u.w);
        }
        int pc = pcnt[node];
        const int* sp = ssrc + ((size_t)node << 6);
        gather16<8>(hp, sp, 0, cq, a);   // slots 0..15 (sentinels past pc: +0)
        gather8<8>(hp, sp, 16, cq, a);   // slots 16..23
        for (int j = 24; j < pc; j += 8) gather8<8>(hp, sp, j, cq, a);
        *(uint4*)&As[rloc * LDA + cq * 8] = pack8(a, dinv[node]);
    }
    __syncthreads();

    // ---- MFMA phase: 4 waves x 16 rows ----
    int wave = t >> 6, l = t & 63;
    int ml = l & 15, q = l >> 4;
    int wr = wave * 16;
    f32x4 acc[8];
    #pragma unroll
    for (int nf = 0; nf < 8; nf++) acc[nf] = (f32x4){0.f, 0.f, 0.f, 0.f};
    const bf16x8* wp8 = (const bf16x8*)Wp;
    #pragma unroll
    for (int ks = 0; ks < 2; ks++) {
        bf16x8 af = *(const bf16x8*)&As[(wr + ml) * LDA + ks * 32 + q * 8];
        bf16x8 bfr[8];
        #pragma unroll
        for (int nf = 0; nf < 8; nf++)
            bfr[nf] = wp8[(size_t)(nf * 2 + ks) * 64 + l];
        #pragma unroll
        for (int nf = 0; nf < 8; nf++)
            acc[nf] = __builtin_amdgcn_mfma_f32_16x16x32_bf16(
                af, bfr[nf], acc[nf], 0, 0, 0);
    }
    float bj[8];
    #pragma unroll
    for (int nf = 0; nf < 8; nf++) bj[nf] = bias[nf * 16 + ml];
    #pragma unroll
    for (int r = 0; r < 4; r++) {
        int row = R0 + wr + q * 4 + r;
        float dv = dinv[row];
        #pragma unroll
        for (int nf = 0; nf < 8; nf++) {
            float v = dv * selu_f(acc[nf][r] + bj[nf]);
            hs2[(size_t)row * 128 + nf * 16 + ml] = f2bf(v);
        }
    }
}

// ---------------------------------------------------------------------------
// GCN2 fused (verified r6 form): gather(128ch) into LDS once (branch-free
// common path), loop 4 column-blocks of the K=128 N=512 MFMA + column max.
// ---------------------------------------------------------------------------
__global__ __launch_bounds__(256) void agg_gemm2_kernel(
    const unsigned short* __restrict__ hs, const float* __restrict__ dinv,
    const int* __restrict__ pcnt, const int* __restrict__ ssrc,
    const unsigned short* __restrict__ Wp, const float* __restrict__ bias,
    unsigned int* __restrict__ menc) {
    constexpr int KS = 4;
    constexpr int LDA = 136;  // 128 + 8
    __shared__ unsigned short As[64 * LDA];
    __shared__ float redf[4 * 128];
    int t = threadIdx.x;
    int R0 = blockIdx.x * 64;
    const uint4* hp = (const uint4*)hs;

    // ---- gather phase: TPN=16, 16 nodes per pass, 4 passes ----
    #pragma unroll
    for (int pass = 0; pass < 4; pass++) {
        int rloc = pass * 16 + (t >> 4);
        int node = R0 + rloc;
        int cq = t & 15;
        float a[8];
        {
            uint4 u = hp[(size_t)node * 16 + cq];
            a[0] = bflo(u.x); a[1] = bfhi(u.x);
            a[2] = bflo(u.y); a[3] = bfhi(u.y);
            a[4] = bflo(u.z); a[5] = bfhi(u.z);
            a[6] = bflo(u.w); a[7] = bfhi(u.w);
        }
        int pc = pcnt[node];
        const int* sp = ssrc + ((size_t)node << 6);
        gather16<16>(hp, sp, 0, cq, a);   // slots 0..15 (sentinels past pc: +0)
        gather8<16>(hp, sp, 16, cq, a);   // slots 16..23
        for (int j = 24; j < pc; j += 8) gather8<16>(hp, sp, j, cq, a);
        *(uint4*)&As[rloc * LDA + cq * 8] = pack8(a, dinv[node]);
    }
    __syncthreads();

    // ---- MFMA phase: 4 waves x 16 rows, loop over 4 column-blocks ----
    int wave = t >> 6, l = t & 63;
    int ml = l & 15, q = l >> 4;
    int wr = wave * 16;
    int b = blockIdx.x >> 6;  // 64 row-tiles per batch
    const bf16x8* wp8 = (const bf16x8*)Wp;
    for (int cbi = 0; cbi < 4; cbi++) {
        f32x4 acc[8];
        #pragma unroll
        for (int nf = 0; nf < 8; nf++) acc[nf] = (f32x4){0.f, 0.f, 0.f, 0.f};
        #pragma unroll
        for (int ks = 0; ks < KS; ks++) {
            bf16x8 af = *(const bf16x8*)&As[(wr + ml) * LDA + ks * 32 + q * 8];
            bf16x8 bfr[8];
            #pragma unroll
            for (int nf = 0; nf < 8; nf++)
                bfr[nf] = wp8[(size_t)((cbi * 8 + nf) * KS + ks) * 64 + l];
            #pragma unroll
            for (int nf = 0; nf < 8; nf++)
                acc[nf] = __builtin_amdgcn_mfma_f32_16x16x32_bf16(
                    af, bfr[nf], acc[nf], 0, 0, 0);
        }
        // selu + column max; C/D layout: col = ml, row = q*4 + r
        float cmax[8];
        #pragma unroll
        for (int nf = 0; nf < 8; nf++) {
            float bj = bias[cbi * 128 + nf * 16 + ml];
            float v = -INFINITY;
            #pragma unroll
            for (int r = 0; r < 4; r++)
                v = fmaxf(v, selu_f(acc[nf][r] + bj));
            v = fmaxf(v, __shfl_xor(v, 16, 64));
            v = fmaxf(v, __shfl_xor(v, 32, 64));
            cmax[nf] = v;
        }
        __syncthreads();  // redf free (prev cbi readers done)
        if (ml == l) {  // lanes 0..15
            #pragma unroll
            for (int nf = 0; nf < 8; nf++) redf[wave * 128 + nf * 16 + l] = cmax[nf];
        }
        __syncthreads();
        if (t < 128) {
            float v = redf[t];
            v = fmaxf(v, redf[128 + t]);
            v = fmaxf(v, redf[256 + t]);
            v = fmaxf(v, redf[384 + t]);
            atomicMax(&menc[b * 512 + cbi * 128 + t], fenc(v));
        }
    }
}

// ---------------------------------------------------------------------------
// lat: grid (8 batches, 16 col-groups of 32).  lat[b][c] =
// selu(sum_k m[b][k]*w_e2[k][c] + b_e2[c]).  k split 8 ways, LDS reduce.
// ---------------------------------------------------------------------------
__global__ __launch_bounds__(256) void lat_kernel(
    const unsigned int* __restrict__ menc, const float* __restrict__ w_e2,
    const float* __restrict__ b_e2, float* __restrict__ lat) {
    int b = blockIdx.x;
    int cg = blockIdx.y;
    int t = threadIdx.x;
    __shared__ float ml[512];
    __shared__ float red[8][32];
    ml[t] = fdec(menc[b * 512 + t]);
    ml[t + 256] = fdec(menc[b * 512 + t + 256]);
    __syncthreads();
    int cl = t & 31;          // column within group
    int kg = t >> 5;          // 0..7, k-chunks of 64
    int c = cg * 32 + cl;
    const float* wp = w_e2 + (size_t)(kg * 64) * 512 + c;
    const float* mlp = ml + kg * 64;
    float acc = 0.f;
    #pragma unroll 16
    for (int k = 0; k < 64; k++) acc = fmaf(mlp[k], wp[(size_t)k * 512], acc);
    red[kg][cl] = acc;
    __syncthreads();
    if (t < 32) {
        float v = ((red[0][t] + red[1][t]) + (red[2][t] + red[3][t])) +
                  ((red[4][t] + red[5][t]) + (red[6][t] + red[7][t]));
        lat[b * 512 + cg * 32 + t] = selu_f(v + b_e2[cg * 32 + t]);
    }
}

// ---------------------------------------------------------------------------
// latw + decode: 64 blocks = 8 batches x 8 point-slices.  Each block
// recomputes the tiny latw reduction (512x6) then decodes its 512 points.
// ---------------------------------------------------------------------------
__global__ __launch_bounds__(256) void latw_decode_kernel(
    const float* __restrict__ lat, const float* __restrict__ w_d1,
    const float* __restrict__ b_d1, const float* __restrict__ w_d2,
    const float* __restrict__ b_d2, float* __restrict__ out) {
    int b = blockIdx.x >> 3;   // batch
    int sl = blockIdx.x & 7;   // point slice
    int t = threadIdx.x;
    __shared__ float ll[512];
    __shared__ float red[6][256];
    __shared__ float lw[6];
    ll[t] = lat[b * 512 + t];
    ll[t + 256] = lat[b * 512 + t + 256];
    __syncthreads();
    float p[6] = {0.f, 0.f, 0.f, 0.f, 0.f, 0.f};
    for (int k = t; k < 512; k += 256) {
        float lv = ll[k];
        #pragma unroll
        for (int j = 0; j < 3; j++) {
            p[j]     = fmaf(lv, w_d1[k * 3 + j], p[j]);
            p[3 + j] = fmaf(lv, w_d2[k * 3 + j], p[3 + j]);
        }
    }
    #pragma unroll
    for (int j = 0; j < 6; j++) red[j][t] = p[j];
    __syncthreads();
    for (int s = 128; s > 0; s >>= 1) {
        if (t < s) {
            #pragma unroll
            for (int j = 0; j < 6; j++) red[j][t] += red[j][t + s];
        }
        __syncthreads();
    }
    if (t < 3) {
        lw[t]     = red[t][0] + b_d1[t];
        lw[3 + t] = red[3 + t][0] + b_d2[t];
    }
    __syncthreads();
    float l10 = lw[0], l11 = lw[1], l12 = lw[2];
    float l20 = lw[3], l21 = lw[4], l22 = lw[5];
    float w1a0 = w_d1[1536 + 0], w1a1 = w_d1[1536 + 1], w1a2 = w_d1[1536 + 2];
    float w1b0 = w_d1[1539 + 0], w1b1 = w_d1[1539 + 1], w1b2 = w_d1[1539 + 2];
    float w2a0 = w_d2[1536 + 0], w2a1 = w_d2[1536 + 1], w2a2 = w_d2[1536 + 2];
    float w2b0 = w_d2[1539 + 0], w2b1 = w_d2[1539 + 1], w2b2 = w_d2[1539 + 2];
    float w2c0 = w_d2[1542 + 0], w2c1 = w_d2[1542 + 1], w2c2 = w_d2[1542 + 2];
    {
        int n = sl * 512 + t;
        #pragma unroll
        for (int half = 0; half < 2; half++) {
            int i = n / 46;
            int j = n - i * 46;
            float y0 = fmaf((float)i, 119.f / 90.f, 1.f);
            float y1 = fmaf((float)j, 59.f / 45.f, 1.f);
            float k0 = selu_f(l10 + y0 * w1a0 + y1 * w1b0);
            float k1 = selu_f(l11 + y0 * w1a1 + y1 * w1b1);
            float k2 = selu_f(l12 + y0 * w1a2 + y1 * w1b2);
            float o0 = selu_f(l20 + k0 * w2a0 + k1 * w2b0 + k2 * w2c0);
            float o1 = selu_f(l21 + k0 * w2a1 + k1 * w2b1 + k2 * w2c1);
            float o2 = selu_f(l22 + k0 * w2a2 + k1 * w2b2 + k2 * w2c2);
            size_t pidx = (size_t)(b * 4096 + n) * 3;
            out[pidx + 0] = o0;
            out[pidx + 1] = o1;
            out[pidx + 2] = o2;
            n += 256;
        }
    }
}

// ---------------------------------------------------------------------------
extern "C" void kernel_launch(void* const* d_in, const int* in_sizes, int n_in,
                              void* d_out, int out_size, void* d_ws, size_t ws_size,
                              hipStream_t stream) {
    const float* x    = (const float*)d_in[0];
    const int*   knn  = (const int*)d_in[1];
    const float* w_e1 = (const float*)d_in[2];
    const float* b_e1 = (const float*)d_in[3];
    const float* w_g1 = (const float*)d_in[4];
    const float* b_g1 = (const float*)d_in[5];
    const float* w_g2 = (const float*)d_in[6];
    const float* b_g2 = (const float*)d_in[7];
    const float* w_e2 = (const float*)d_in[8];
    const float* b_e2 = (const float*)d_in[9];
    const float* w_d1 = (const float*)d_in[10];
    const float* b_d1 = (const float*)d_in[11];
    const float* w_d2 = (const float*)d_in[12];
    const float* b_d2 = (const float*)d_in[13];
    float* out = (float*)d_out;

    const int BN = in_sizes[0] / 3;   // 32768
    const int E  = in_sizes[1] / 2;   // 524288
    const int Bb = BN / 4096;         // 8
    const int* src = knn;
    const int* dst = knn + E;

    size_t off = 0;
    auto alloc = [&](size_t bytes) -> void* {
        void* p = (char*)d_ws + off;
        off += (bytes + 255) & ~(size_t)255;
        return p;
    };
    unsigned short* hs1 = (unsigned short*)alloc((size_t)(BN + 1) * 64 * 2);
    unsigned short* hs2 = (unsigned short*)alloc((size_t)(BN + 1) * 128 * 2);
    unsigned short* Wp1 = (unsigned short*)alloc((size_t)16 * 64 * 8 * 2);
    unsigned short* Wp2 = (unsigned short*)alloc((size_t)128 * 64 * 8 * 2);
    unsigned int* menc = (unsigned int*)alloc((size_t)Bb * 512 * 4);
    float* lat    = (float*)alloc((size_t)Bb * 512 * 4);
    float* dinv   = (float*)alloc((size_t)BN * 4);
    int*   cnt    = (int*)alloc((size_t)BN * 4);
    int*   pcnt   = (int*)alloc((size_t)BN * 4);
    int*   ssrc   = (int*)alloc((size_t)BN * 64 * 4);
    (void)ws_size;

    // prep: zero cnt + sentinel rows + m_enc, pack both weight matrices
    prep_kernel<<<273, 256, 0, stream>>>(
        cnt, (unsigned int*)(hs1 + (size_t)BN * 64),
        (unsigned int*)(hs2 + (size_t)BN * 128), menc, w_g1, Wp1, w_g2, Wp2);
    // count + direct scatter, 2 edges/thread
    count_scatter_kernel<<<(E / 2 + 255) / 256, 256, 0, stream>>>(src, dst, cnt, ssrc, E);
    // dinv + padded counts + sentinel pad-fill (>=24) + cov/encoder (fused)
    padfill_cov_kernel<<<BN / 128, 128, 0, stream>>>(
        cnt, dinv, pcnt, ssrc, BN, x, w_e1, b_e1, hs1);

    // GCN1 fused: gather(64) -> MFMA K=64 -> bf16 hs2 (prescaled); M=64
    agg_gemm1_kernel<<<BN / 64, 256, 0, stream>>>(hs1, dinv, pcnt, ssrc, Wp1, b_g1, hs2);

    // GCN2 fused: gather(128) -> MFMA K=128 N=512 + column max; M=64
    agg_gemm2_kernel<<<BN / 64, 256, 0, stream>>>(hs2, dinv, pcnt, ssrc, Wp2, b_g2, menc);

    // latent matmul, parallel over 8x16 blocks
    lat_kernel<<<dim3(Bb, 16), 256, 0, stream>>>(menc, w_e2, b_e2, lat);

    // latw + decode (64 blocks: 8 batches x 8 slices)
    latw_decode_kernel<<<Bb * 8, 256, 0, stream>>>(lat, w_d1, b_d1, w_d2, b_d2, out);
}